// Round 1
// 422.976 us; speedup vs baseline: 1.0509x; 1.0509x over previous
//
#include <hip/hip_runtime.h>

// rFFT-512 via radix-2 Stockham on packed complex-256, one wave (64 lanes) per row.
// re[b,t,r] = sum_n x[n] cos(2*pi*r*n/512); im[b,t,r] = -sum_n x[n] sin(2*pi*r*n/512)
//
// Round 1 changes vs baseline (VALU-bound per rocprof: VALUBusy~105%, HBM 29%):
//  1. sincosf -> hardware v_sin_f32/v_cos_f32 via __builtin_amdgcn_{sin,cos}f.
//     HW ops take REVOLUTIONS; all twiddle angles are t/256 or k/512 revolutions
//     with small integer t,k -> no range reduction needed. ~60 VALU ops -> ~4.
//  2. __syncthreads -> wave-local s_waitcnt lgkmcnt(0): the LDS ping-pong
//     buffers are per-wave (bufA[wid]), so no cross-wave dependence exists.

#define NFFT 512
#define NH 256         // packed complex FFT size
#define NRFFT 257
#define RPB 4          // rows per block (one wave each)

__device__ __forceinline__ void wave_lds_fence() {
    // All lanes of the wave have issued their ds ops in program order; drain
    // them before dependent reads. Buffers are wave-private, so no s_barrier.
    asm volatile("s_waitcnt lgkmcnt(0)" ::: "memory");
}

__global__ __launch_bounds__(256) void rfft512_kernel(const float* __restrict__ x,
                                                      float* __restrict__ out_re,
                                                      float* __restrict__ out_im,
                                                      int nrows) {
    __shared__ float2 bufA[RPB][NH];
    __shared__ float2 bufB[RPB][NH];

    const int lane = threadIdx.x & 63;
    const int wid  = threadIdx.x >> 6;
    const int row  = blockIdx.x * RPB + wid;
    if (row >= nrows) return;   // wave-uniform; no block-wide barriers anywhere

    // ---- load row: x[2n],x[2n+1] pairs are exactly the row reinterpreted as float2
    {
        const float4* x4 = reinterpret_cast<const float4*>(x + (size_t)row * NFFT);
        float4* a4 = reinterpret_cast<float4*>(&bufA[wid][0]);
        a4[lane]      = x4[lane];
        a4[lane + 64] = x4[lane + 64];
    }
    wave_lds_fence();

    // ---- Stockham radix-2 forward FFT, n=256, 8 stages, ping-pong A<->B
    const float INV256 = 0.00390625f;   // 1/256, exact
    float2* X = &bufA[wid][0];
    float2* Y = &bufB[wid][0];
    #pragma unroll
    for (int m = 1; m <= 128; m <<= 1) {
        #pragma unroll
        for (int bb = 0; bb < 2; ++bb) {
            const int b = lane + bb * 64;       // butterfly index 0..127
            const int t = b & ~(m - 1);         // twiddle numerator (j*m)
            const float2 c0 = X[b];
            const float2 c1 = X[b + 128];
            const float tf = (float)t * INV256;            // revolutions in [0, 0.5)
            const float c  =  __builtin_amdgcn_cosf(tf);   // cos(2*pi*t/256)
            const float s  = -__builtin_amdgcn_sinf(tf);   // -sin(2*pi*t/256)
            float2 sum = {c0.x + c1.x, c0.y + c1.y};
            float2 dif = {c0.x - c1.x, c0.y - c1.y};
            float2 tw  = {c * dif.x - s * dif.y, c * dif.y + s * dif.x};
            Y[b + t]     = sum;
            Y[b + t + m] = tw;
        }
        { float2* tmp = X; X = Y; Y = tmp; }   // 8 swaps -> result ends in bufA
        wave_lds_fence();
    }

    // ---- untangle packed real FFT and store k = 0..256
    {
        const float INV512 = 0.001953125f;  // 1/512, exact
        float* orr = out_re + (size_t)row * NRFFT;
        float* oir = out_im + (size_t)row * NRFFT;
        #pragma unroll
        for (int kk = 0; kk < 4; ++kk) {
            const int k = lane + kk * 64;
            if (k == 0) {
                const float2 z0 = X[0];
                orr[0]   = z0.x + z0.y;  oir[0]   = 0.0f;
                orr[256] = z0.x - z0.y;  oir[256] = 0.0f;
            } else {
                const float2 zk = X[k];
                const float2 zm = X[256 - k];
                const float ze_re = 0.5f * (zk.x + zm.x);
                const float ze_im = 0.5f * (zk.y - zm.y);
                const float zo_re = 0.5f * (zk.y + zm.y);
                const float zo_im = -0.5f * (zk.x - zm.x);
                const float tf = (float)k * INV512;            // revolutions in (0, 0.5]
                const float c  =  __builtin_amdgcn_cosf(tf);   // cos(2*pi*k/512)
                const float s  = -__builtin_amdgcn_sinf(tf);   // -sin(2*pi*k/512)
                orr[k] = ze_re + c * zo_re - s * zo_im;
                oir[k] = ze_im + c * zo_im + s * zo_re;
            }
        }
    }
}

extern "C" void kernel_launch(void* const* d_in, const int* in_sizes, int n_in,
                              void* d_out, int out_size, void* d_ws, size_t ws_size,
                              hipStream_t stream) {
    const float* x = (const float*)d_in[0];
    // d_in[1]/d_in[2] (m_real/m_imag) unused: twiddles computed analytically.
    float* out = (float*)d_out;
    const int nrows = in_sizes[0] / NFFT;            // 32*4000 = 128000
    float* out_re = out;
    float* out_im = out + (size_t)nrows * NRFFT;     // outputs concatenated flat
    const int blocks = (nrows + RPB - 1) / RPB;      // 32000
    rfft512_kernel<<<blocks, 256, 0, stream>>>(x, out_re, out_im, nrows);
}